// Round 8
// baseline (254.592 us; speedup 1.0000x reference)
//
#include <hip/hip_runtime.h>
#include <hip/hip_bf16.h>
#include <stdint.h>

#define SEQ    2048
#define NBATCH 4
#define NHEADS 16
#define DHEAD  64
#define MODELD 1024
#define QKVN   1152          // 1024 q + 64 k + 64 v columns
#define MROWS  (NBATCH*SEQ)  // 8192
// exp(s*0.125) == exp2(s * 0.125 * log2(e)); folded into w_q at transpose time
#define SCALE_LOG2E 0.1803368801111244f

typedef __bf16 bf16x8 __attribute__((ext_vector_type(8)));
typedef float  f32x4  __attribute__((ext_vector_type(4)));

typedef __attribute__((address_space(1))) void* as1_void_p;
typedef __attribute__((address_space(3))) void* as3_void_p;

__device__ __forceinline__ void gld_lds16(const void* g, void* l) {
  __builtin_amdgcn_global_load_lds((as1_void_p)(g), (as3_void_p)(l), 16, 0, 0);
}

__device__ __forceinline__ ushort f2bf(float f) {
  union { float f; uint32_t i; } t; t.f = f;
  uint32_t r = (t.i + 0x7fffu + ((t.i >> 16) & 1u)) >> 16;
  return (ushort)r;
}
__device__ __forceinline__ uint32_t pack_bf16(float a, float b) {
  union { __hip_bfloat162 h2; uint32_t u; } cv;
  cv.h2 = __float22bfloat162_rn(make_float2(a, b));
  return cv.u;
}

// ---------------- fused prep: x convert + 3 weight transposes ----------------
__device__ __forceinline__ void do_transpose(const float* __restrict__ src,
                                             ushort* __restrict__ dst,
                                             int R, int C, float scale,
                                             int gx, int gy, int tid) {
  __shared__ float tile[32][33];
  const int tx = tid & 31, ty = tid >> 5;  // ty in 0..7
  const int c0 = gx * 32, r0 = gy * 32;
#pragma unroll
  for (int j = 0; j < 4; j++)
    tile[ty*4 + j][tx] = src[(size_t)(r0 + ty*4 + j) * C + c0 + tx];
  __syncthreads();
#pragma unroll
  for (int j = 0; j < 4; j++)
    dst[(size_t)(c0 + ty*4 + j) * R + r0 + tx] = f2bf(tile[tx][ty*4 + j] * scale);
}

__global__ __launch_bounds__(256)
void prep(const float* __restrict__ x, const float* __restrict__ w_q,
          const float* __restrict__ w_kv, const float* __restrict__ w_out,
          ushort* __restrict__ xb, ushort* __restrict__ wqkvT,
          ushort* __restrict__ woutT) {
  const int bid = blockIdx.x, tid = threadIdx.x;
  if (bid < 8192) {                      // x -> bf16, 1024 elems/block
    const size_t i = ((size_t)bid * 256 + tid) * 4;
    const float4 v = *(const float4*)(x + i);
    ushort4 o;
    o.x = f2bf(v.x); o.y = f2bf(v.y); o.z = f2bf(v.z); o.w = f2bf(v.w);
    *(ushort4*)(xb + i) = o;
  } else if (bid < 9216) {               // w_q^T (scale folded)
    const int t = bid - 8192;
    do_transpose(w_q, wqkvT, MODELD, MODELD, SCALE_LOG2E, t & 31, t >> 5, tid);
  } else if (bid < 9344) {               // w_kv^T -> rows 1024..1151
    const int t = bid - 9216;
    do_transpose(w_kv, wqkvT + (size_t)MODELD * MODELD, MODELD, 128, 1.0f,
                 t & 3, t >> 2, tid);
  } else {                               // w_out^T
    const int t = bid - 9344;
    do_transpose(w_out, woutT, MODELD, MODELD, 1.0f, t & 31, t >> 5, tid);
  }
}

// ------- GEMM v2: deep-pipelined ring-4, counted vmcnt (T3+T4) --------------
// C(M x N) = A(M x K) * Bt(N x K)^T (+bias), bf16 in. K = 1024 fixed (NT=32).
// BM=128, BN=256, BK=32; 8 waves (2M x 4N), wave out 64x64, 16 MFMA/tile/wave.
// Ring of 4 K-tile LDS slots (96 KB): stage tile t+3 while computing tile t.
//   - before tile t: exactly 6 of this wave's loads outstanding (tiles t+1,t+2;
//     3 loads/thread/tile) -> s_waitcnt vmcnt(6), NEVER 0 in the main loop.
//   - slot (t+3)&3 was last read at tile t-1; every wave's t-1 reads completed
//     before its tile-t barrier (reads consumed by MFMAs) -> overwrite is safe.
//   - raw asm s_barrier (memory clobber): no compiler-inserted vmcnt(0) drain.
// BK=32 => 64B LDS rows: gld_lds writes and b128 frag reads both hit the
// structural 8-lane/4-bank-group minimum -> no swizzle needed.
// K accumulation order identical to the R6 kernel -> bit-identical numerics.
// nB = valid B rows (N): staging rows clamped, stores guarded (handles N=1152
// with a partial 5th col-tile; no padding anywhere).
template <bool OUT_F32>
__global__ __launch_bounds__(512, 1)
void gemm_bt2(const ushort* __restrict__ A, const ushort* __restrict__ Bt,
              void* __restrict__ Cp, const float* __restrict__ bias,
              ushort* __restrict__ VT,
              int lda, int ldb, int ldc, int nB) {
  __shared__ __attribute__((aligned(16))) ushort As[4][128*32];
  __shared__ __attribute__((aligned(16))) ushort Bs[4][256*32];
  const int tid = threadIdx.x;
  const int w = tid >> 6, lane = tid & 63;
  const int quad = lane >> 4, m16 = lane & 15;
  const int wr = w >> 2, wc = w & 3;          // 2M x 4N wave grid

  // bijective XCD swizzle (m204); nwg = 320 or 256, both % 8 == 0
  const int nwg = gridDim.x * gridDim.y;
  const int orig = blockIdx.y * gridDim.x + blockIdx.x;
  const int qq = nwg >> 3, rr = nwg & 7;
  const int xcd = orig & 7, loc = orig >> 3;
  const int L = (xcd < rr ? xcd * (qq + 1) : rr * (qq + 1) + (xcd - rr) * qq) + loc;
  const int bm0 = (L / gridDim.x) * 128, bn0 = (L % gridDim.x) * 256;

  f32x4 acc[4][4] = {};

  // staging: per tile, 3 gld_lds/thread (1 A + 2 B). thread -> row tid>>2,
  // 16B granule tid&3. Wave w writes rows [w*16, w*16+16) of each 128-row slab.
  const int srA = tid >> 2, sgv = (tid & 3) * 8;
  const ushort* Ag = A + (size_t)(bm0 + srA) * lda + sgv;
  int brow0 = bn0 + srA;        if (brow0 >= nB) brow0 = nB - 1;
  int brow1 = bn0 + 128 + srA;  if (brow1 >= nB) brow1 = nB - 1;
  const ushort* Bg0 = Bt + (size_t)brow0 * ldb + sgv;
  const ushort* Bg1 = Bt + (size_t)brow1 * ldb + sgv;

#define STAGE(u) {                                              \
    const int s_ = (u) & 3;                                     \
    gld_lds16(Ag  + (u)*32, &As[s_][(w*16)*32]);                \
    gld_lds16(Bg0 + (u)*32, &Bs[s_][(w*16)*32]);                \
    gld_lds16(Bg1 + (u)*32, &Bs[s_][(128 + w*16)*32]); }

#define BODY(t) {                                               \
    const int s_ = (t) & 3;                                     \
    const ushort* Asl = As[s_];                                 \
    const ushort* Bsl = Bs[s_];                                 \
    bf16x8 af[4], bf0[2], bf1[2];                               \
    _Pragma("unroll")                                           \
    for (int mi = 0; mi < 4; mi++)                              \
      af[mi] = *(const bf16x8*)(Asl + (wr*64 + mi*16 + m16)*32 + quad*8); \
    _Pragma("unroll")                                           \
    for (int j = 0; j < 2; j++)                                 \
      bf0[j] = *(const bf16x8*)(Bsl + (wc*64 + j*16 + m16)*32 + quad*8);  \
    __builtin_amdgcn_s_setprio(1);                              \
    _Pragma("unroll")                                           \
    for (int mi = 0; mi < 4; mi++)                              \
      _Pragma("unroll")                                         \
      for (int j = 0; j < 2; j++)                               \
        acc[mi][j] = __builtin_amdgcn_mfma_f32_16x16x32_bf16(af[mi], bf0[j], acc[mi][j], 0, 0, 0); \
    __builtin_amdgcn_s_setprio(0);                              \
    _Pragma("unroll")                                           \
    for (int j = 0; j < 2; j++)                                 \
      bf1[j] = *(const bf16x8*)(Bsl + (wc*64 + (2+j)*16 + m16)*32 + quad*8); \
    __builtin_amdgcn_s_setprio(1);                              \
    _Pragma("unroll")                                           \
    for (int mi = 0; mi < 4; mi++)                              \
      _Pragma("unroll")                                         \
      for (int j = 0; j < 2; j++)                               \
        acc[mi][2+j] = __builtin_amdgcn_mfma_f32_16x16x32_bf16(af[mi], bf1[j], acc[mi][2+j], 0, 0, 0); \
    __builtin_amdgcn_s_setprio(0); }

  // prologue: stage tiles 0,1,2 (9 loads outstanding)
  STAGE(0); STAGE(1); STAGE(2);

  // main loop: tiles 0..29. vmcnt(6) retires tile t's 3 loads (oldest).
#pragma unroll 1
  for (int t = 0; t < 30; ++t) {
    asm volatile("s_waitcnt vmcnt(6)" ::: "memory");
    asm volatile("s_barrier" ::: "memory");
    if (t <= 28) STAGE(t + 3);
    BODY(t);
  }
  asm volatile("s_waitcnt vmcnt(3)" ::: "memory");  // tile 30 ready (31 in flight)
  asm volatile("s_barrier" ::: "memory");
  BODY(30);
  asm volatile("s_waitcnt vmcnt(0)" ::: "memory");  // tile 31 ready
  asm volatile("s_barrier" ::: "memory");
  BODY(31);
#undef STAGE
#undef BODY

  // epilogue: C/D layout col=lane&15, row=quad*4+reg
  const bool hasV = (VT != nullptr) && (bn0 + 256 > 1088);
#pragma unroll
  for (int ni = 0; ni < 4; ni++) {
    const int col = bn0 + wc*64 + ni*16 + m16;
    if (col >= nB) continue;                 // partial last col-tile (N=1152)
    const float bv = bias ? bias[col] : 0.0f;
#pragma unroll
    for (int mi = 0; mi < 4; mi++) {
#pragma unroll
      for (int r = 0; r < 4; r++) {
        const int row = bm0 + wr*64 + mi*16 + quad*4 + r;
        const float v = acc[mi][ni][r] + bv;
        if (OUT_F32) ((float*)Cp)[(size_t)row*ldc + col] = v;
        else         ((ushort*)Cp)[(size_t)row*ldc + col] = f2bf(v);
        if (hasV && col >= 1088) {           // V columns -> transposed copy
          const int d = col - 1088, bb = row >> 11, n = row & 2047;
          VT[((size_t)bb * DHEAD + d) * SEQ + n] = f2bf(v);
        }
      }
    }
  }
}

// ---------------- Flash MQA attention, v9: 2 heads/block (R7-verified) -------
// MQA: all heads share K/V; waves 0-3 -> head 2y, waves 4-7 -> head 2y+1,
// shared Ks/Vs staging. 512 blocks = 2/CU, 16 waves/CU.
// LDS 57.6 KB (Ks 9.2K + Vs 11.5K + pbuf[8] 36.9K).
__global__ __launch_bounds__(512, 2)
void mqa_attn(const ushort* __restrict__ qkv, const ushort* __restrict__ vT,
              ushort* __restrict__ attn_out) {
  __shared__ __attribute__((aligned(16))) ushort Ks[64*72];      // K[kv][d], pad 72
  __shared__ __attribute__((aligned(16))) ushort Vs[80*72];      // V^T[d][kv]; rows 64..79 = ones-tile
  __shared__ __attribute__((aligned(16))) ushort pbuf[8][32*72]; // per-wave P[q(32)][64kv], pad 72

  const int tid = threadIdx.x;
  const int w = tid >> 6, lane = tid & 63;
  const int quad = lane >> 4, m16 = lane & 15;
  const int h = blockIdx.y * 2 + (w >> 2);           // 2 heads per block
  const int b = blockIdx.z;
  const size_t rowbase = (size_t)b * SEQ;
  const int q0 = blockIdx.x * 128 + (w & 3) * 32;    // 4 waves cover 128 q-rows/head
  const ushort* vTb = vT + (size_t)b * DHEAD * SEQ;
  ushort* pb = pbuf[w];

  // ones-tile init (once): Vs row 64 = 1.0 (bf16 0x3F80), rows 65..79 = 0.
  for (int i = tid; i < 16*72; i += 512)
    Vs[64*72 + i] = (i < 72) ? (ushort)0x3F80 : (ushort)0;

  // staging map: 512 threads cover the full 64x64 tile in ONE pass
  const int srow = tid >> 3, scol = (tid & 7) * 8;
  const ushort* kgbase = qkv + (rowbase + srow) * QKVN + 1024 + scol;
  const ushort* vgbase = vTb + (size_t)srow * SEQ + scol;

  // persistent Q fragments (B-layout: n=q=m16, k=d=quad*8 (+32)); q pre-scaled
  bf16x8 qf[2][2];
#pragma unroll
  for (int qt = 0; qt < 2; qt++) {
    const ushort* qrow = qkv + (rowbase + q0 + qt*16 + m16) * QKVN + h * DHEAD;
    qf[qt][0] = *(const bf16x8*)(qrow + quad*8);
    qf[qt][1] = *(const bf16x8*)(qrow + 32 + quad*8);
  }

  f32x4 o[2][4] = {};   // O^T tiles [qt][dt], C-layout: row=d=quad*4+r, col=q=m16
  f32x4 o4[2]   = {};   // l-tile: ones-row MFMA accumulator

  // preload chunk 0
  uint4 kreg = *(const uint4*)(kgbase);
  uint4 vreg = *(const uint4*)(vgbase);

  for (int kv0 = 0; kv0 < SEQ; kv0 += 64) {
    __syncthreads();                         // prev chunk's readers done
    *(uint4*)(Ks + srow*72 + scol) = kreg;
    *(uint4*)(Vs + srow*72 + scol) = vreg;
    __syncthreads();                         // staging (+ ones-tile) visible

    // issue NEXT chunk's global loads now
    const int kvn = (kv0 + 64) & (SEQ - 1);
    kreg = *(const uint4*)(kgbase + (size_t)kvn * QKVN);
    vreg = *(const uint4*)(vgbase + kvn);

    // ---- S^T = K Q^T for all 64 kv; p = exp2(s); P -> per-wave LDS ----
#pragma unroll
    for (int kh = 0; kh < 2; kh++) {
#pragma unroll
      for (int t2 = 0; t2 < 2; t2++) {
        const int t = kh*2 + t2;
        const bf16x8 kf0 = *(const bf16x8*)(Ks + (t*16 + m16)*72 + quad*8);
        const bf16x8 kf1 = *(const bf16x8*)(Ks + (t*16 + m16)*72 + 32 + quad*8);
#pragma unroll
        for (int qt = 0; qt < 2; qt++) {
          f32x4 s = {};
          s = __builtin_amdgcn_mfma_f32_16x16x32_bf16(kf0, qf[qt][0], s, 0, 0, 0);
          s = __builtin_amdgcn_mfma_f32_16x16x32_bf16(kf1, qf[qt][1], s, 0, 0, 0);
          float p[4];
#pragma unroll
          for (int r = 0; r < 4; r++)
            p[r] = __builtin_amdgcn_exp2f(s[r]);   // kv=t*16+quad*4+r, q=m16
          *(uint2*)(pb + (qt*16 + m16)*72 + kh*32 + t2*16 + quad*4) =
              make_uint2(pack_bf16(p[0], p[1]), pack_bf16(p[2], p[3]));
        }
      }
    }
    asm volatile("s_waitcnt lgkmcnt(0)" ::: "memory");  // wave-internal P RAW

    // ---- O^T += V^T P^T; l via ones-row MFMA ----
#pragma unroll
    for (int kh = 0; kh < 2; kh++) {
      bf16x8 pf[2], vf[4], vf4;
#pragma unroll
      for (int qt = 0; qt < 2; qt++)
        pf[qt] = *(const bf16x8*)(pb + (qt*16 + m16)*72 + kh*32 + quad*8);
#pragma unroll
      for (int dt = 0; dt < 4; dt++)
        vf[dt] = *(const bf16x8*)(Vs + (dt*16 + m16)*72 + kh*32 + quad*8);
      vf4 = *(const bf16x8*)(Vs + (64 + m16)*72 + kh*32 + quad*8);
      __builtin_amdgcn_s_setprio(1);
#pragma unroll
      for (int qt = 0; qt < 2; qt++) {
#pragma unroll
        for (int dt = 0; dt < 4; dt++)
          o[qt][dt] = __builtin_amdgcn_mfma_f32_16x16x32_bf16(vf[dt], pf[qt], o[qt][dt], 0, 0, 0);
        o4[qt] = __builtin_amdgcn_mfma_f32_16x16x32_bf16(vf4, pf[qt], o4[qt], 0, 0, 0);
      }
      __builtin_amdgcn_s_setprio(0);
    }
  }

  // ---- epilogue ----
#pragma unroll
  for (int qt = 0; qt < 2; qt++) {
    const float l = __shfl(o4[qt][0], m16, 64);
    const float inv = 1.0f / l;
    const size_t row = rowbase + q0 + qt*16 + m16;
#pragma unroll
    for (int dt = 0; dt < 4; dt++) {
      ushort4 st;
      st.x = f2bf(o[qt][dt][0] * inv);
      st.y = f2bf(o[qt][dt][1] * inv);
      st.z = f2bf(o[qt][dt][2] * inv);
      st.w = f2bf(o[qt][dt][3] * inv);
      *(ushort4*)(attn_out + row*MODELD + h*DHEAD + dt*16 + quad*4) = st;
    }
  }
}

// ---------------- launch ----------------
extern "C" void kernel_launch(void* const* d_in, const int* in_sizes, int n_in,
                              void* d_out, int out_size, void* d_ws, size_t ws_size,
                              hipStream_t stream) {
  const float* x     = (const float*)d_in[0];
  const float* w_q   = (const float*)d_in[1];
  const float* w_kv  = (const float*)d_in[2];
  const float* w_out = (const float*)d_in[3];
  const float* b_out = (const float*)d_in[4];

  ushort* wqkvT = (ushort*)d_ws;                         // 1152 x 1024 bf16
  ushort* woutT = wqkvT + (size_t)QKVN * MODELD;         // 1024 x 1024 bf16
  ushort* xb    = woutT + (size_t)MODELD * MODELD;       // 8192 x 1024 bf16
  ushort* qkv   = xb    + (size_t)MROWS * MODELD;        // 8192 x 1152 bf16
  ushort* attn  = qkv   + (size_t)MROWS * QKVN;          // 8192 x 1024 bf16
  ushort* vTb   = attn  + (size_t)MROWS * MODELD;        // 4 x 64 x 2048 bf16 (V^T)

  // fused prep: x->bf16 + 3 weight transposes (scale folded into w_q)
  prep<<<10368, 256, 0, stream>>>(x, w_q, w_kv, w_out, xb, wqkvT, woutT);

  // QKV projection: (8192x1024) @ (1152x1024)^T -> 8192x1152 bf16 (+ V^T)
  // grid (5,64): 5th col-tile partial (cols 1024..1151), clamped/guarded.
  gemm_bt2<false><<<dim3(5, MROWS/128), 512, 0, stream>>>(
      xb, wqkvT, (void*)qkv, nullptr, vTb, MODELD, MODELD, QKVN, QKVN);

  // flash MQA -> attn (8192 x 1024 bf16, col = h*64+d); 2 heads/block
  mqa_attn<<<dim3(SEQ/128, NHEADS/2, NBATCH), 512, 0, stream>>>(qkv, vTb, attn);

  // output projection + bias -> d_out (fp32)
  gemm_bt2<true><<<dim3(4, MROWS/128), 512, 0, stream>>>(
      attn, woutT, d_out, b_out, nullptr, MODELD, MODELD, MODELD, MODELD);
}